// Round 5
// baseline (3827.990 us; speedup 1.0000x reference)
//
#include <hip/hip_runtime.h>
#include <float.h>
#include <math.h>

#define BB 16
#define NN 2048
#define KNNK 20
#define HC 512
#define O5 1024
#define EPSF 1e-5f
#define GBLK 2048   // number of k_gather blocks (= BB*NN/16)

__device__ __forceinline__ float leakyf(float y){ return y > 0.f ? y : 0.2f*y; }

// ---------------- transpose x (B,3,N) -> xP (B,N,4) padded ----------------
__global__ void k_transpose(const float* __restrict__ x, float* __restrict__ xP){
  int gid = blockIdx.x*256 + threadIdx.x;
  if (gid >= BB*NN) return;
  int b = gid / NN, n = gid % NN;
  const float* xb = x + (size_t)b*3*NN;
  *(float4*)&xP[(size_t)gid*4] = make_float4(xb[n], xb[NN + n], xb[2*NN + n], 0.f);
}

// ---------------- squared norms ----------------
__global__ void k_sqn(const float* __restrict__ xin, int xs, int C, float* __restrict__ sqn){
  int gid = blockIdx.x*256 + threadIdx.x;
  if (gid >= BB*NN) return;
  const float* r = xin + (size_t)gid*xs;
  float s = 0.f;
  for (int c = 0; c < C; ++c){ float v = r[c]; s = fmaf(v, v, s); }
  sqn[gid] = s;
}

// ---------------- KNN: 16 waves/block, ONE row per wave ----------------
// 1024 threads = 16 waves; wave w owns query row w; lane owns m-cols lane*4..+3 per chunk.
// __launch_bounds__(1024, 4): 128-VGPR budget — R4's (1024,8) forced 32 VGPR -> scratch spills
// (WRITE_SIZE 49MB/dispatch). Compiler should land ~64 VGPR -> no spill, 8 waves/EU possible.
template<int C>
__global__ __launch_bounds__(1024, 4) void k_knn(const float* __restrict__ xin, int xs,
                                                 const float* __restrict__ sqn,
                                                 int* __restrict__ idx_out){
  const int TN = 16, MC = 256;
  __shared__ float xnT[(C < 8 ? 8 : C)][TN + 4];
  __shared__ float xmT[(C == 3 ? 1 : 16)][MC + 4];
  __shared__ float cval[TN][24];
  __shared__ int   cidx[TN][24];
  int tid = threadIdx.x;
  int b = (blockIdx.x*TN) / NN, n0 = (blockIdx.x*TN) % NN;
  const float* xb = xin + (size_t)b*NN*xs;

  for (int e = tid; e < TN*C; e += 1024){
    int rr = e / C, c = e % C;
    xnT[c][rr] = xb[(size_t)(n0+rr)*xs + c];
  }
  __syncthreads();

  int wid = tid >> 6, lane = tid & 63;
  const int r = wid;
  float sqr = sqn[b*NN + n0 + r];
  float tv; int ti;

  for (int base = 0; base < NN; base += MC){
    float pd[4];
    if constexpr (C == 3){
      int m0g = base + lane*4;
      const float* xm = xb + (size_t)m0g*4;
      float4 q0 = *(const float4*)&xm[0];
      float4 q1 = *(const float4*)&xm[4];
      float4 q2 = *(const float4*)&xm[8];
      float4 q3 = *(const float4*)&xm[12];
      float4 sm4 = *(const float4*)&sqn[b*NN + m0g];
      float a0 = xnT[0][r], a1 = xnT[1][r], a2 = xnT[2][r];
      float d0 = a0*q0.x; d0 = fmaf(a1, q0.y, d0); d0 = fmaf(a2, q0.z, d0);
      float d1 = a0*q1.x; d1 = fmaf(a1, q1.y, d1); d1 = fmaf(a2, q1.z, d1);
      float d2 = a0*q2.x; d2 = fmaf(a1, q2.y, d2); d2 = fmaf(a2, q2.z, d2);
      float d3 = a0*q3.x; d3 = fmaf(a1, q3.y, d3); d3 = fmaf(a2, q3.z, d3);
      pd[0] = (2.f*d0 - sqr) - sm4.x;
      pd[1] = (2.f*d1 - sqr) - sm4.y;
      pd[2] = (2.f*d2 - sqr) - sm4.z;
      pd[3] = (2.f*d3 - sqr) - sm4.w;
    } else {
      float acc[4] = {0.f, 0.f, 0.f, 0.f};
      int sm_ = tid >> 2, sc_ = (tid & 3) << 2;
      for (int c0 = 0; c0 < C; c0 += 16){
        float4 vv = *(const float4*)&xb[(size_t)(base + sm_)*xs + c0 + sc_];
        __syncthreads();   // protect prior reads of xmT
        xmT[sc_+0][sm_] = vv.x; xmT[sc_+1][sm_] = vv.y;
        xmT[sc_+2][sm_] = vv.z; xmT[sc_+3][sm_] = vv.w;
        __syncthreads();
        #pragma unroll
        for (int cc = 0; cc < 16; ++cc){
          float a = xnT[c0+cc][r];
          float4 m4 = *(const float4*)&xmT[cc][lane*4];
          acc[0] = fmaf(a, m4.x, acc[0]);
          acc[1] = fmaf(a, m4.y, acc[1]);
          acc[2] = fmaf(a, m4.z, acc[2]);
          acc[3] = fmaf(a, m4.w, acc[3]);
        }
      }
      float4 sm4 = *(const float4*)&sqn[b*NN + base + lane*4];
      pd[0] = (2.f*acc[0] - sqr) - sm4.x;
      pd[1] = (2.f*acc[1] - sqr) - sm4.y;
      pd[2] = (2.f*acc[2] - sqr) - sm4.z;
      pd[3] = (2.f*acc[3] - sqr) - sm4.w;
    }

    if (base == 0){
      // build sorted top-20 via register extraction
      float lv = pd[0]; int lj = 0;
      if (pd[1] > lv){ lv = pd[1]; lj = 1; }
      if (pd[2] > lv){ lv = pd[2]; lj = 2; }
      if (pd[3] > lv){ lv = pd[3]; lj = 3; }
      int li = lane*4 + lj;
      float bv = -FLT_MAX; int bi = 0;
      for (int it = 0; it < KNNK; ++it){
        bv = lv; bi = li;
        #pragma unroll
        for (int off = 1; off < 64; off <<= 1){
          float ov = __shfl_xor(bv, off, 64);
          int oi = __shfl_xor(bi, off, 64);
          if (ov > bv || (ov == bv && oi < bi)){ bv = ov; bi = oi; }
        }
        if (lane == it){ cval[r][it] = bv; cidx[r][it] = bi; }
        int wl = bi >> 2, wj = bi & 3;
        if (lane == wl){
          pd[0] = (wj == 0) ? -FLT_MAX : pd[0];
          pd[1] = (wj == 1) ? -FLT_MAX : pd[1];
          pd[2] = (wj == 2) ? -FLT_MAX : pd[2];
          pd[3] = (wj == 3) ? -FLT_MAX : pd[3];
          lv = pd[0]; lj = 0;
          if (pd[1] > lv){ lv = pd[1]; lj = 1; }
          if (pd[2] > lv){ lv = pd[2]; lj = 2; }
          if (pd[3] > lv){ lv = pd[3]; lj = 3; }
          li = lane*4 + lj;
        }
      }
      tv = bv; ti = bi;   // 20th best = threshold (uniform via butterfly)
    } else {
      bool pred = false;
      #pragma unroll
      for (int j = 0; j < 4; ++j){
        int ci = base + lane*4 + j;
        pred = pred || (pd[j] > tv) || (pd[j] == tv && ci < ti);
      }
      unsigned long long mask = __ballot(pred);
      while (mask){
        int l = __builtin_ctzll(mask); mask &= (mask - 1);
        float cv0 = __shfl(pd[0], l);
        float cv1 = __shfl(pd[1], l);
        float cv2 = __shfl(pd[2], l);
        float cv3 = __shfl(pd[3], l);
        #pragma unroll
        for (int j = 0; j < 4; ++j){
          float cv = (j == 0) ? cv0 : (j == 1) ? cv1 : (j == 2) ? cv2 : cv3;
          int ci = base + l*4 + j;
          if (cv > tv || (cv == tv && ci < ti)){
            float ev = -FLT_MAX; int ei = 0x7fffffff;
            if (lane < KNNK){ ev = cval[r][lane]; ei = cidx[r][lane]; }
            bool ahead = (lane < KNNK) && (ev > cv || (ev == cv && ei < ci));
            int pos = __popcll(__ballot(ahead));
            float pev = __shfl_up(ev, 1);
            int   pei = __shfl_up(ei, 1);
            float nv; int ni;
            if (lane < pos){ nv = ev; ni = ei; }
            else if (lane == pos){ nv = cv; ni = ci; }
            else { nv = pev; ni = pei; }
            if (lane < KNNK){ cval[r][lane] = nv; cidx[r][lane] = ni; }
            tv = __shfl(nv, 19); ti = __shfl(ni, 19);
          }
        }
      }
    }
  }

  if (lane < KNNK)
    idx_out[(size_t)(b*NN + n0 + r)*KNNK + lane] = cidx[r][lane];
}

// ---------------- weight prep ----------------
__global__ void k_wprep(const float* __restrict__ W, int O, int C,
                        float* __restrict__ wu, float* __restrict__ wv){
  int i = blockIdx.x*256 + threadIdx.x;
  if (i >= O*C) return;
  int o = i / C, c = i % C;
  float a = W[(size_t)o*2*C + c], b = W[(size_t)o*2*C + C + c];
  wu[i] = a; wv[i] = b - a;
}

// ---------------- u,v GEMM ----------------
__global__ __launch_bounds__(256) void k_uv(const float* __restrict__ xin, int xs, int C,
                                            const float* __restrict__ wu, const float* __restrict__ wv,
                                            int O, float* __restrict__ u, float* __restrict__ v){
  __shared__ float xsh[16][68];
  __shared__ float wush[16][68], wvsh[16][68];
  int tid = threadIdx.x;
  int rb = blockIdx.x*64, ob = blockIdx.y*64;
  int otx = tid % 16, rty = tid / 16;
  float au[4][4] = {}, av[4][4] = {};
  for (int c0 = 0; c0 < C; c0 += 16){
    #pragma unroll
    for (int i = 0; i < 4; ++i){
      int c = otx, r = rty*4 + i;
      xsh[c][r]  = (c0 + c < C) ? xin[(size_t)(rb+r)*xs + c0 + c] : 0.f;
      wush[c][r] = (c0 + c < C) ? wu[(size_t)(ob+r)*C + c0 + c] : 0.f;
      wvsh[c][r] = (c0 + c < C) ? wv[(size_t)(ob+r)*C + c0 + c] : 0.f;
    }
    __syncthreads();
    #pragma unroll
    for (int c = 0; c < 16; ++c){
      float4 xr = *(const float4*)&xsh[c][rty*4];
      float4 wa = *(const float4*)&wush[c][otx*4];
      float4 wb = *(const float4*)&wvsh[c][otx*4];
      float xv[4] = {xr.x, xr.y, xr.z, xr.w};
      float wav[4] = {wa.x, wa.y, wa.z, wa.w};
      float wbv[4] = {wb.x, wb.y, wb.z, wb.w};
      #pragma unroll
      for (int i = 0; i < 4; ++i)
        #pragma unroll
        for (int j = 0; j < 4; ++j){
          au[i][j] = fmaf(xv[i], wav[j], au[i][j]);
          av[i][j] = fmaf(xv[i], wbv[j], av[i][j]);
        }
    }
    __syncthreads();
  }
  #pragma unroll
  for (int i = 0; i < 4; ++i){
    size_t r = (size_t)(rb + rty*4 + i);
    *(float4*)&u[r*O + ob + otx*4] = make_float4(au[i][0], au[i][1], au[i][2], au[i][3]);
    *(float4*)&v[r*O + ob + otx*4] = make_float4(av[i][0], av[i][1], av[i][2], av[i][3]);
  }
}

// ---------------- gather + max/sum/sumsq -> deterministic partials ----------------
__global__ __launch_bounds__(256) void k_gather(const float* __restrict__ u, const float* __restrict__ v,
                                                const int* __restrict__ idx, int O,
                                                float* __restrict__ s,
                                                float* __restrict__ gp1, float* __restrict__ gp2){
  __shared__ float r1[256], r2[256];
  int tid = threadIdx.x;
  int Ppar = 256 / O;
  int o = tid % O, g = tid / O;
  int p0 = blockIdx.x*16;
  float cs = 0.f, cs2 = 0.f;
  int IT = 16 / Ppar;
  for (int it = 0; it < IT; ++it){
    int pi = p0 + it*Ppar + g;
    int b = pi / NN;
    const int* il = idx + (size_t)pi*KNNK;
    float vv = v[(size_t)pi*O + o];
    float mx = -FLT_MAX, su = 0.f, su2 = 0.f;
    #pragma unroll
    for (int k = 0; k < KNNK; ++k){
      int m = il[k];
      float um = u[((size_t)b*NN + m)*O + o];
      mx = fmaxf(mx, um); su += um; su2 = fmaf(um, um, su2);
    }
    s[(size_t)pi*O + o] = mx + vv;
    cs += su + (float)KNNK*vv;
    cs2 += su2 + 2.f*vv*su + (float)KNNK*vv*vv;
  }
  r1[tid] = cs; r2[tid] = cs2;
  __syncthreads();
  if (tid < O){
    float t1 = 0.f, t2 = 0.f;
    for (int gg = 0; gg < Ppar; ++gg){ t1 += r1[gg*O + tid]; t2 += r2[gg*O + tid]; }
    gp1[(size_t)tid*GBLK + blockIdx.x] = t1;
    gp2[(size_t)tid*GBLK + blockIdx.x] = t2;
  }
}

// ---------------- deterministic partial reduce: one block per channel ----------------
__global__ __launch_bounds__(256) void k_pred(const float* __restrict__ gp1, const float* __restrict__ gp2,
                                              float* __restrict__ S1, float* __restrict__ S2){
  __shared__ float r1[256], r2[256];
  int o = blockIdx.x, t = threadIdx.x;
  float a = 0.f, b = 0.f;
  #pragma unroll
  for (int i = 0; i < GBLK/256; ++i){
    a += gp1[(size_t)o*GBLK + i*256 + t];
    b += gp2[(size_t)o*GBLK + i*256 + t];
  }
  r1[t] = a; r2[t] = b;
  __syncthreads();
  for (int off = 128; off > 0; off >>= 1){
    if (t < off){ r1[t] += r1[t + off]; r2[t] += r2[t + off]; }
    __syncthreads();
  }
  if (t == 0){ S1[o] = r1[0]; S2[o] = r2[0]; }
}

// ---------------- finalize BN ----------------
__global__ void k_fin(const float* __restrict__ S1, const float* __restrict__ S2,
                      const float* __restrict__ g, const float* __restrict__ bb,
                      int O, float cnt, float* __restrict__ A, float* __restrict__ Bp){
  int o = blockIdx.x*256 + threadIdx.x;
  if (o >= O) return;
  float m = S1[o] / cnt;
  float var = S2[o] / cnt - m*m;
  float sc = g[o] / sqrtf(var + EPSF);
  A[o] = sc; Bp[o] = bb[o] - m*sc;
}

// ---------------- BN + leaky -> h slice ----------------
__global__ void k_bnle(const float* __restrict__ s, const float* __restrict__ A,
                       const float* __restrict__ Bp, int O, int choff, float* __restrict__ h){
  int gid = blockIdx.x*256 + threadIdx.x;
  int row = gid / O, o = gid % O;
  h[(size_t)row*HC + choff + o] = leakyf(fmaf(s[gid], A[o], Bp[o]));
}

// ---------------- column sums of h -> 16 deterministic partials ----------------
__global__ void k_colsum(const float* __restrict__ hh, float* __restrict__ cp){
  __shared__ float red[4][64];
  int c = threadIdx.x & 63, g = threadIdx.x >> 6;
  int cb = blockIdx.x*64;
  int rbase = blockIdx.y*2048;
  float sacc = 0.f;
  for (int r = rbase + g; r < rbase + 2048; r += 4)
    sacc += hh[(size_t)r*HC + cb + c];
  red[g][c] = sacc;
  __syncthreads();
  if (threadIdx.x < 64){
    float t = red[0][c] + red[1][c] + red[2][c] + red[3][c];
    cp[(size_t)blockIdx.y*HC + cb + c] = t;
  }
}

__global__ void k_csred(const float* __restrict__ cp, float* __restrict__ cs){
  int c = blockIdx.x*256 + threadIdx.x;
  if (c >= HC) return;
  float s = 0.f;
  for (int g = 0; g < 16; ++g) s += cp[(size_t)g*HC + c];
  cs[c] = s;
}

// ---------------- SYRK partials ----------------
__global__ __launch_bounds__(256) void k_syrk(const float* __restrict__ hh, float* __restrict__ Gp){
  __shared__ float as[16][132], bs[16][132];
  int tid = threadIdx.x;
  int ib = blockIdx.x*128, jb = blockIdx.y*128;
  int k0 = blockIdx.z*1024;
  int cx = tid & 15, ry = tid >> 4;
  int skk = tid >> 4, scc = (tid & 15)*8;
  float acc[8][8] = {};
  for (int kk0 = k0; kk0 < k0 + 1024; kk0 += 16){
    {
      const float* ra = &hh[(size_t)(kk0 + skk)*HC + ib + scc];
      const float* rb2 = &hh[(size_t)(kk0 + skk)*HC + jb + scc];
      float4 a0 = *(const float4*)ra, a1 = *(const float4*)(ra + 4);
      float4 b0 = *(const float4*)rb2, b1 = *(const float4*)(rb2 + 4);
      *(float4*)&as[skk][scc] = a0; *(float4*)&as[skk][scc+4] = a1;
      *(float4*)&bs[skk][scc] = b0; *(float4*)&bs[skk][scc+4] = b1;
    }
    __syncthreads();
    #pragma unroll
    for (int kk = 0; kk < 16; ++kk){
      float4 a0 = *(const float4*)&as[kk][ry*8];
      float4 a1 = *(const float4*)&as[kk][ry*8+4];
      float4 b0 = *(const float4*)&bs[kk][cx*8];
      float4 b1 = *(const float4*)&bs[kk][cx*8+4];
      float av[8] = {a0.x,a0.y,a0.z,a0.w,a1.x,a1.y,a1.z,a1.w};
      float bv[8] = {b0.x,b0.y,b0.z,b0.w,b1.x,b1.y,b1.z,b1.w};
      #pragma unroll
      for (int i = 0; i < 8; ++i)
        #pragma unroll
        for (int j = 0; j < 8; ++j)
          acc[i][j] = fmaf(av[i], bv[j], acc[i][j]);
    }
    __syncthreads();
  }
  float* gz = Gp + (size_t)blockIdx.z*HC*HC;
  #pragma unroll
  for (int i = 0; i < 8; ++i){
    size_t row = (size_t)(ib + ry*8 + i);
    *(float4*)&gz[row*HC + jb + cx*8]     = make_float4(acc[i][0], acc[i][1], acc[i][2], acc[i][3]);
    *(float4*)&gz[row*HC + jb + cx*8 + 4] = make_float4(acc[i][4], acc[i][5], acc[i][6], acc[i][7]);
  }
}

// ---------------- reduce SYRK partials ----------------
__global__ void k_gred(const float* __restrict__ Gp, float* __restrict__ G){
  int e = blockIdx.x*256 + threadIdx.x;
  float s = 0.f;
  for (int z = 0; z < 32; ++z) s += Gp[(size_t)z*HC*HC + e];
  G[e] = s;
}

// ---------------- quadratic forms ----------------
__global__ __launch_bounds__(256) void k_quad(const float* __restrict__ G, const float* __restrict__ W5,
                                              const float* __restrict__ cs,
                                              float* __restrict__ S1, float* __restrict__ S2){
  __shared__ float wsh[512];
  __shared__ float red[256];
  int o = blockIdx.x, tid = threadIdx.x;
  for (int j = tid; j < 512; j += 256) wsh[j] = W5[(size_t)o*HC + j];
  __syncthreads();
  float q = 0.f;
  for (int i = tid; i < 512; i += 256){
    float wi = wsh[i];
    float rd = 0.f;
    for (int j = 0; j < 512; j += 4){
      float4 gv = *(const float4*)&G[(size_t)i*HC + j];
      rd = fmaf(gv.x, wsh[j], rd); rd = fmaf(gv.y, wsh[j+1], rd);
      rd = fmaf(gv.z, wsh[j+2], rd); rd = fmaf(gv.w, wsh[j+3], rd);
    }
    q = fmaf(wi, rd, q);
  }
  float m = 0.f;
  for (int j = tid; j < 512; j += 256) m = fmaf(wsh[j], cs[j], m);
  red[tid] = q; __syncthreads();
  for (int off = 128; off > 0; off >>= 1){ if (tid < off) red[tid] += red[tid + off]; __syncthreads(); }
  if (tid == 0) S2[o] = red[0];
  __syncthreads();
  red[tid] = m; __syncthreads();
  for (int off = 128; off > 0; off >>= 1){ if (tid < off) red[tid] += red[tid + off]; __syncthreads(); }
  if (tid == 0) S1[o] = red[0];
}

// ---------------- layer5 GEMM: y tile -> BN+leaky -> pooled partials ----------------
__global__ __launch_bounds__(256) void k_gemm5b(const float* __restrict__ hh, const float* __restrict__ W5,
                                                const float* __restrict__ A, const float* __restrict__ Bp,
                                                float* __restrict__ mpart, float* __restrict__ spart){
  __shared__ float hs[16][132];
  __shared__ float ws[16][132];
  int tid = threadIdx.x;
  int rb = blockIdx.x*128, ob = blockIdx.y*128;
  int cx = tid & 15, ry = tid >> 4;
  float acc[8][8] = {};
  for (int c0 = 0; c0 < 512; c0 += 16){
    int rr = tid & 127, q0 = (tid >> 7)*4;
    #pragma unroll
    for (int qq = 0; qq < 2; ++qq){
      int kk = q0 + qq*8;
      float4 hv = *(const float4*)&hh[(size_t)(rb+rr)*HC + c0 + kk];
      hs[kk+0][rr] = hv.x; hs[kk+1][rr] = hv.y; hs[kk+2][rr] = hv.z; hs[kk+3][rr] = hv.w;
      float4 wv = *(const float4*)&W5[(size_t)(ob+rr)*HC + c0 + kk];
      ws[kk+0][rr] = wv.x; ws[kk+1][rr] = wv.y; ws[kk+2][rr] = wv.z; ws[kk+3][rr] = wv.w;
    }
    __syncthreads();
    #pragma unroll
    for (int kk = 0; kk < 16; ++kk){
      float4 a0 = *(const float4*)&hs[kk][ry*8];
      float4 a1 = *(const float4*)&hs[kk][ry*8+4];
      float4 b0 = *(const float4*)&ws[kk][cx*8];
      float4 b1 = *(const float4*)&ws[kk][cx*8+4];
      float av[8] = {a0.x,a0.y,a0.z,a0.w,a1.x,a1.y,a1.z,a1.w};
      float bv[8] = {b0.x,b0.y,b0.z,b0.w,b1.x,b1.y,b1.z,b1.w};
      #pragma unroll
      for (int i = 0; i < 8; ++i)
        #pragma unroll
        for (int j = 0; j < 8; ++j)
          acc[i][j] = fmaf(av[i], bv[j], acc[i][j]);
    }
    __syncthreads();
  }
  float Ao[8], Bo[8];
  #pragma unroll
  for (int j = 0; j < 8; ++j){ Ao[j] = A[ob + cx*8 + j]; Bo[j] = Bp[ob + cx*8 + j]; }
  float cmx[8], csm[8];
  #pragma unroll
  for (int j = 0; j < 8; ++j){ cmx[j] = -FLT_MAX; csm[j] = 0.f; }
  #pragma unroll
  for (int i = 0; i < 8; ++i)
    #pragma unroll
    for (int j = 0; j < 8; ++j){
      float a = leakyf(fmaf(acc[i][j], Ao[j], Bo[j]));
      cmx[j] = fmaxf(cmx[j], a); csm[j] += a;
    }
  __syncthreads();
  #pragma unroll
  for (int j = 0; j < 8; ++j){ hs[ry][cx*8 + j] = cmx[j]; ws[ry][cx*8 + j] = csm[j]; }
  __syncthreads();
  if (tid < 128){
    float mx = -FLT_MAX, sm = 0.f;
    for (int g = 0; g < 16; ++g){ mx = fmaxf(mx, hs[g][tid]); sm += ws[g][tid]; }
    int bbi = rb / NN, ntile = (rb % NN) >> 7;
    int o = ob + tid;
    mpart[((size_t)bbi*O5 + o)*16 + ntile] = mx;
    spart[((size_t)bbi*O5 + o)*16 + ntile] = sm;
  }
}

// ---------------- pool partials -> p ----------------
__global__ void k_pool(const float* __restrict__ mpart, const float* __restrict__ spart,
                       float* __restrict__ p){
  int gid = blockIdx.x*256 + threadIdx.x;
  if (gid >= BB*O5) return;
  int b = gid / O5, o = gid % O5;
  const float* mp = mpart + (size_t)(b*O5 + o)*16;
  const float* sp = spart + (size_t)(b*O5 + o)*16;
  float mx = -FLT_MAX, sm = 0.f;
  for (int t = 0; t < 16; ++t){ mx = fmaxf(mx, mp[t]); sm += sp[t]; }
  p[(size_t)b*2048 + o] = mx;
  p[(size_t)b*2048 + 1024 + o] = sm * (1.f/2048.f);
}

// ---------------- z = p @ Wl.T then BN over batch ----------------
__global__ __launch_bounds__(256) void k_final(const float* __restrict__ p, const float* __restrict__ Wl,
                                               const float* __restrict__ g6, const float* __restrict__ b6,
                                               float* __restrict__ out){
  __shared__ float red[16][257];
  int oc = blockIdx.x, tid = threadIdx.x;
  float acc[16] = {};
  for (int j = tid; j < 2048; j += 256){
    float w = Wl[(size_t)oc*2048 + j];
    #pragma unroll
    for (int b = 0; b < 16; ++b) acc[b] = fmaf(p[(size_t)b*2048 + j], w, acc[b]);
  }
  #pragma unroll
  for (int b = 0; b < 16; ++b) red[b][tid] = acc[b];
  __syncthreads();
  for (int off = 128; off > 0; off >>= 1){
    if (tid < off){
      #pragma unroll
      for (int b = 0; b < 16; ++b) red[b][tid] += red[b][tid + off];
    }
    __syncthreads();
  }
  if (tid == 0){
    float m = 0.f;
    for (int b = 0; b < 16; ++b) m += red[b][0];
    m *= (1.f/16.f);
    float var = 0.f;
    for (int b = 0; b < 16; ++b){ float d = red[b][0] - m; var = fmaf(d, d, var); }
    var *= (1.f/16.f);
    float sc = g6[oc] / sqrtf(var + EPSF);
    for (int b = 0; b < 16; ++b) out[(size_t)b*256 + oc] = (red[b][0] - m)*sc + b6[oc];
  }
}

extern "C" void kernel_launch(void* const* d_in, const int* in_sizes, int n_in,
                              void* d_out, int out_size, void* d_ws, size_t ws_size,
                              hipStream_t stream){
  const float* x  = (const float*)d_in[0];
  const float* W1 = (const float*)d_in[1];  const float* g1 = (const float*)d_in[2];  const float* b1 = (const float*)d_in[3];
  const float* W2 = (const float*)d_in[4];  const float* g2 = (const float*)d_in[5];  const float* b2 = (const float*)d_in[6];
  const float* W3 = (const float*)d_in[7];  const float* g3 = (const float*)d_in[8];  const float* b3 = (const float*)d_in[9];
  const float* W4 = (const float*)d_in[10]; const float* g4 = (const float*)d_in[11]; const float* b4 = (const float*)d_in[12];
  const float* W5 = (const float*)d_in[13]; const float* g5 = (const float*)d_in[14]; const float* b5 = (const float*)d_in[15];
  const float* Wl = (const float*)d_in[16]; const float* g6 = (const float*)d_in[17]; const float* b6 = (const float*)d_in[18];
  float* out = (float*)d_out;

  float* ws = (float*)d_ws;
  size_t off = 0;
  auto alloc = [&](size_t n){ float* pp = ws + off; off += n; return pp; };
  float* h    = alloc((size_t)BB*NN*HC);     // 64 MB
  float* u    = alloc((size_t)BB*NN*256);    // 32 MB (aliased by Gp after layer 4)
  float* v    = alloc((size_t)BB*NN*256);
  float* s    = alloc((size_t)BB*NN*256);
  float* xP   = alloc((size_t)BB*NN*4);
  float* sqn  = alloc((size_t)BB*NN);
  int*   idx  = (int*)alloc((size_t)BB*NN*KNNK);
  float* wu   = alloc(256*128);
  float* wv   = alloc(256*128);
  float* S1   = alloc(1024);
  float* S2   = alloc(1024);
  float* Ab   = alloc(1024);
  float* Bb   = alloc(1024);
  float* mpart= alloc((size_t)BB*O5*16);
  float* spart= alloc((size_t)BB*O5*16);
  float* pbuf = alloc((size_t)BB*2048);
  float* G    = alloc((size_t)HC*HC);
  float* cs   = alloc(HC);
  float* cp   = alloc((size_t)16*HC);
  float* gp1  = alloc((size_t)256*GBLK);     // 2 MB deterministic gather partials
  float* gp2  = alloc((size_t)256*GBLK);
  float* Gp   = u;   // 32 z-chunks x 512x512 = 32 MB, reuses u (dead after layer 4)

  k_transpose<<<(BB*NN)/256, 256, 0, stream>>>(x, xP);

  struct Cfg { const float* xin; int xs, C, O, choff; const float* W; const float* g; const float* bb; };
  Cfg cfg[4] = {
    { xP,    4,   3,   64,   0, W1, g1, b1 },
    { h,     HC,  64,  64,  64, W2, g2, b2 },
    { h+64,  HC,  64, 128, 128, W3, g3, b3 },
    { h+128, HC, 128, 256, 256, W4, g4, b4 },
  };

  for (int i = 0; i < 4; ++i){
    const Cfg& c = cfg[i];
    k_sqn<<<(BB*NN)/256, 256, 0, stream>>>(c.xin, c.xs, c.C, sqn);
    if (c.C == 3)       k_knn<3><<<(BB*NN)/16, 1024, 0, stream>>>(c.xin, c.xs, sqn, idx);
    else if (c.C == 64) k_knn<64><<<(BB*NN)/16, 1024, 0, stream>>>(c.xin, c.xs, sqn, idx);
    else                k_knn<128><<<(BB*NN)/16, 1024, 0, stream>>>(c.xin, c.xs, sqn, idx);
    int OC = c.O * c.C;
    k_wprep<<<(OC + 255)/256, 256, 0, stream>>>(c.W, c.O, c.C, wu, wv);
    k_uv<<<dim3((BB*NN)/64, c.O/64), 256, 0, stream>>>(c.xin, c.xs, c.C, wu, wv, c.O, u, v);
    k_gather<<<GBLK, 256, 0, stream>>>(u, v, idx, c.O, s, gp1, gp2);
    k_pred<<<c.O, 256, 0, stream>>>(gp1, gp2, S1, S2);
    k_fin<<<4, 256, 0, stream>>>(S1, S2, c.g, c.bb, c.O, (float)((size_t)BB*NN*KNNK), Ab, Bb);
    k_bnle<<<((size_t)BB*NN*c.O)/256, 256, 0, stream>>>(s, Ab, Bb, c.O, c.choff, h);
  }

  // layer 5 stats via covariance: S2 = w^T (h^T h) w, S1 = w . colsum(h)
  k_colsum<<<dim3(8, 16), 256, 0, stream>>>(h, cp);
  k_csred<<<2, 256, 0, stream>>>(cp, cs);
  k_syrk<<<dim3(4, 4, 32), 256, 0, stream>>>(h, Gp);
  k_gred<<<(HC*HC)/256, 256, 0, stream>>>(Gp, G);
  k_quad<<<O5, 256, 0, stream>>>(G, W5, cs, S1, S2);
  k_fin<<<4, 256, 0, stream>>>(S1, S2, g5, b5, O5, (float)((size_t)BB*NN), Ab, Bb);
  k_gemm5b<<<dim3((BB*NN)/128, O5/128), 256, 0, stream>>>(h, W5, Ab, Bb, mpart, spart);
  k_pool<<<(BB*O5)/256, 256, 0, stream>>>(mpart, spart, pbuf);

  k_final<<<256, 256, 0, stream>>>(pbuf, Wl, g6, b6, out);
}

// Round 6
// 3034.522 us; speedup vs baseline: 1.2615x; 1.2615x over previous
//
#include <hip/hip_runtime.h>
#include <float.h>
#include <math.h>

#define BB 16
#define NN 2048
#define KNNK 20
#define HC 512
#define O5 1024
#define EPSF 1e-5f
#define GBLK 2048   // number of k_gather blocks (= BB*NN/16)

__device__ __forceinline__ float leakyf(float y){ return y > 0.f ? y : 0.2f*y; }

// ---------------- transpose x (B,3,N) -> xP (B,N,4) padded ----------------
__global__ void k_transpose(const float* __restrict__ x, float* __restrict__ xP){
  int gid = blockIdx.x*256 + threadIdx.x;
  if (gid >= BB*NN) return;
  int b = gid / NN, n = gid % NN;
  const float* xb = x + (size_t)b*3*NN;
  *(float4*)&xP[(size_t)gid*4] = make_float4(xb[n], xb[NN + n], xb[2*NN + n], 0.f);
}

// ---------------- squared norms ----------------
__global__ void k_sqn(const float* __restrict__ xin, int xs, int C, float* __restrict__ sqn){
  int gid = blockIdx.x*256 + threadIdx.x;
  if (gid >= BB*NN) return;
  const float* r = xin + (size_t)gid*xs;
  float s = 0.f;
  for (int c = 0; c < C; ++c){ float v = r[c]; s = fmaf(v, v, s); }
  sqn[gid] = s;
}

// ---------------- KNN: R3 structure (256 thr, 4 waves x 4 rows) ----------------
// Change vs R3: chunk-0 extraction interleaves the 4 rows' shfl butterflies
// (loop interchange) -> 4 independent dependency chains in flight per wave.
template<int C>
__global__ __launch_bounds__(256) void k_knn(const float* __restrict__ xin, int xs,
                                             const float* __restrict__ sqn,
                                             int* __restrict__ idx_out){
  const int TN = 16, MC = 256;
  __shared__ float xnT[(C < 8 ? 8 : C)][20];
  __shared__ float xmT[16][MC + 4];
  __shared__ float cval[TN][24];
  __shared__ int   cidx[TN][24];
  __shared__ float sqnn[TN];
  int tid = threadIdx.x;
  int b = (blockIdx.x*TN) / NN, n0 = (blockIdx.x*TN) % NN;
  const float* xb = xin + (size_t)b*NN*xs;

  for (int e = tid; e < TN*C; e += 256){
    int r = e / C, c = e % C;
    xnT[c][r] = xb[(size_t)(n0+r)*xs + c];
  }
  if (tid < TN) sqnn[tid] = sqn[b*NN + n0 + tid];
  __syncthreads();

  int wid = tid >> 6, lane = tid & 63, r0 = wid*4;
  float tv[4]; int ti[4];

  for (int base = 0; base < NN; base += MC){
    float pd[4][4];
    if constexpr (C == 3){
      int m0g = base + lane*4;
      const float* xm = xb + (size_t)m0g*4;
      float4 q0 = *(const float4*)&xm[0];
      float4 q1 = *(const float4*)&xm[4];
      float4 q2 = *(const float4*)&xm[8];
      float4 q3 = *(const float4*)&xm[12];
      float4 sm4 = *(const float4*)&sqn[b*NN + m0g];
      #pragma unroll
      for (int i = 0; i < 4; ++i){
        float a0 = xnT[0][r0+i], a1 = xnT[1][r0+i], a2 = xnT[2][r0+i], sq = sqnn[r0+i];
        float d0 = a0*q0.x; d0 = fmaf(a1, q0.y, d0); d0 = fmaf(a2, q0.z, d0);
        float d1 = a0*q1.x; d1 = fmaf(a1, q1.y, d1); d1 = fmaf(a2, q1.z, d1);
        float d2 = a0*q2.x; d2 = fmaf(a1, q2.y, d2); d2 = fmaf(a2, q2.z, d2);
        float d3 = a0*q3.x; d3 = fmaf(a1, q3.y, d3); d3 = fmaf(a2, q3.z, d3);
        pd[i][0] = (2.f*d0 - sq) - sm4.x;
        pd[i][1] = (2.f*d1 - sq) - sm4.y;
        pd[i][2] = (2.f*d2 - sq) - sm4.z;
        pd[i][3] = (2.f*d3 - sq) - sm4.w;
      }
    } else {
      float acc[4][4] = {};
      for (int c0 = 0; c0 < C; c0 += 16){
        const float* xr = xb + (size_t)(base + tid)*xs + c0;
        #pragma unroll
        for (int cc = 0; cc < 16; cc += 4){
          float4 vv = *(const float4*)(xr + cc);
          xmT[cc][tid] = vv.x; xmT[cc+1][tid] = vv.y; xmT[cc+2][tid] = vv.z; xmT[cc+3][tid] = vv.w;
        }
        __syncthreads();
        #pragma unroll
        for (int cc = 0; cc < 16; ++cc){
          float4 a4 = *(const float4*)&xnT[c0+cc][r0];
          float4 m4 = *(const float4*)&xmT[cc][lane*4];
          float av[4] = {a4.x, a4.y, a4.z, a4.w};
          float mv[4] = {m4.x, m4.y, m4.z, m4.w};
          #pragma unroll
          for (int i = 0; i < 4; ++i)
            #pragma unroll
            for (int j = 0; j < 4; ++j)
              acc[i][j] = fmaf(av[i], mv[j], acc[i][j]);
        }
        __syncthreads();
      }
      float4 sm4 = *(const float4*)&sqn[b*NN + base + lane*4];
      float smr[4] = {sm4.x, sm4.y, sm4.z, sm4.w};
      #pragma unroll
      for (int i = 0; i < 4; ++i){
        float sq = sqnn[r0+i];
        #pragma unroll
        for (int j = 0; j < 4; ++j)
          pd[i][j] = (2.f*acc[i][j] - sq) - smr[j];
      }
    }

    if (base == 0){
      // interleaved extraction: 4 rows advance together per iteration
      float lv[4]; int li[4];
      #pragma unroll
      for (int i = 0; i < 4; ++i){
        float v0 = pd[i][0]; int j0 = 0;
        if (pd[i][1] > v0){ v0 = pd[i][1]; j0 = 1; }
        if (pd[i][2] > v0){ v0 = pd[i][2]; j0 = 2; }
        if (pd[i][3] > v0){ v0 = pd[i][3]; j0 = 3; }
        lv[i] = v0; li[i] = lane*4 + j0;
      }
      float bv[4]; int bi[4];
      for (int it = 0; it < KNNK; ++it){
        #pragma unroll
        for (int i = 0; i < 4; ++i){ bv[i] = lv[i]; bi[i] = li[i]; }
        #pragma unroll
        for (int off = 1; off < 64; off <<= 1){
          #pragma unroll
          for (int i = 0; i < 4; ++i){
            float ov = __shfl_xor(bv[i], off, 64);
            int oi = __shfl_xor(bi[i], off, 64);
            if (ov > bv[i] || (ov == bv[i] && oi < bi[i])){ bv[i] = ov; bi[i] = oi; }
          }
        }
        #pragma unroll
        for (int i = 0; i < 4; ++i){
          if (lane == it){ cval[r0+i][it] = bv[i]; cidx[r0+i][it] = bi[i]; }
          int wl = bi[i] >> 2, wj = bi[i] & 3;
          if (lane == wl){
            pd[i][0] = (wj == 0) ? -FLT_MAX : pd[i][0];
            pd[i][1] = (wj == 1) ? -FLT_MAX : pd[i][1];
            pd[i][2] = (wj == 2) ? -FLT_MAX : pd[i][2];
            pd[i][3] = (wj == 3) ? -FLT_MAX : pd[i][3];
            float v0 = pd[i][0]; int j0 = 0;
            if (pd[i][1] > v0){ v0 = pd[i][1]; j0 = 1; }
            if (pd[i][2] > v0){ v0 = pd[i][2]; j0 = 2; }
            if (pd[i][3] > v0){ v0 = pd[i][3]; j0 = 3; }
            lv[i] = v0; li[i] = lane*4 + j0;
          }
        }
      }
      #pragma unroll
      for (int i = 0; i < 4; ++i){ tv[i] = bv[i]; ti[i] = bi[i]; }  // 20th best
    } else {
      #pragma unroll
      for (int i = 0; i < 4; ++i){
        int r = r0 + i;
        bool pred = false;
        #pragma unroll
        for (int j = 0; j < 4; ++j){
          int ci = base + lane*4 + j;
          pred = pred || (pd[i][j] > tv[i]) || (pd[i][j] == tv[i] && ci < ti[i]);
        }
        unsigned long long mask = __ballot(pred);
        while (mask){
          int l = __builtin_ctzll(mask); mask &= (mask - 1);
          float cv0 = __shfl(pd[i][0], l);
          float cv1 = __shfl(pd[i][1], l);
          float cv2 = __shfl(pd[i][2], l);
          float cv3 = __shfl(pd[i][3], l);
          #pragma unroll
          for (int j = 0; j < 4; ++j){
            float cv = (j == 0) ? cv0 : (j == 1) ? cv1 : (j == 2) ? cv2 : cv3;
            int ci = base + l*4 + j;
            if (cv > tv[i] || (cv == tv[i] && ci < ti[i])){
              float ev = -FLT_MAX; int ei = 0x7fffffff;
              if (lane < KNNK){ ev = cval[r][lane]; ei = cidx[r][lane]; }
              bool ahead = (lane < KNNK) && (ev > cv || (ev == cv && ei < ci));
              int pos = __popcll(__ballot(ahead));
              float pev = __shfl_up(ev, 1);
              int   pei = __shfl_up(ei, 1);
              float nv; int ni;
              if (lane < pos){ nv = ev; ni = ei; }
              else if (lane == pos){ nv = cv; ni = ci; }
              else { nv = pev; ni = pei; }
              if (lane < KNNK){ cval[r][lane] = nv; cidx[r][lane] = ni; }
              tv[i] = __shfl(nv, 19); ti[i] = __shfl(ni, 19);
            }
          }
        }
      }
    }
  }

  if (lane < KNNK){
    #pragma unroll
    for (int i = 0; i < 4; ++i){
      int r = r0 + i;
      idx_out[(size_t)(b*NN + n0 + r)*KNNK + lane] = cidx[r][lane];
    }
  }
}

// ---------------- weight prep ----------------
__global__ void k_wprep(const float* __restrict__ W, int O, int C,
                        float* __restrict__ wu, float* __restrict__ wv){
  int i = blockIdx.x*256 + threadIdx.x;
  if (i >= O*C) return;
  int o = i / C, c = i % C;
  float a = W[(size_t)o*2*C + c], b = W[(size_t)o*2*C + C + c];
  wu[i] = a; wv[i] = b - a;
}

// ---------------- u,v GEMM ----------------
__global__ __launch_bounds__(256) void k_uv(const float* __restrict__ xin, int xs, int C,
                                            const float* __restrict__ wu, const float* __restrict__ wv,
                                            int O, float* __restrict__ u, float* __restrict__ v){
  __shared__ float xsh[16][68];
  __shared__ float wush[16][68], wvsh[16][68];
  int tid = threadIdx.x;
  int rb = blockIdx.x*64, ob = blockIdx.y*64;
  int otx = tid % 16, rty = tid / 16;
  float au[4][4] = {}, av[4][4] = {};
  for (int c0 = 0; c0 < C; c0 += 16){
    #pragma unroll
    for (int i = 0; i < 4; ++i){
      int c = otx, r = rty*4 + i;
      xsh[c][r]  = (c0 + c < C) ? xin[(size_t)(rb+r)*xs + c0 + c] : 0.f;
      wush[c][r] = (c0 + c < C) ? wu[(size_t)(ob+r)*C + c0 + c] : 0.f;
      wvsh[c][r] = (c0 + c < C) ? wv[(size_t)(ob+r)*C + c0 + c] : 0.f;
    }
    __syncthreads();
    #pragma unroll
    for (int c = 0; c < 16; ++c){
      float4 xr = *(const float4*)&xsh[c][rty*4];
      float4 wa = *(const float4*)&wush[c][otx*4];
      float4 wb = *(const float4*)&wvsh[c][otx*4];
      float xv[4] = {xr.x, xr.y, xr.z, xr.w};
      float wav[4] = {wa.x, wa.y, wa.z, wa.w};
      float wbv[4] = {wb.x, wb.y, wb.z, wb.w};
      #pragma unroll
      for (int i = 0; i < 4; ++i)
        #pragma unroll
        for (int j = 0; j < 4; ++j){
          au[i][j] = fmaf(xv[i], wav[j], au[i][j]);
          av[i][j] = fmaf(xv[i], wbv[j], av[i][j]);
        }
    }
    __syncthreads();
  }
  #pragma unroll
  for (int i = 0; i < 4; ++i){
    size_t r = (size_t)(rb + rty*4 + i);
    *(float4*)&u[r*O + ob + otx*4] = make_float4(au[i][0], au[i][1], au[i][2], au[i][3]);
    *(float4*)&v[r*O + ob + otx*4] = make_float4(av[i][0], av[i][1], av[i][2], av[i][3]);
  }
}

// ---------------- gather + max/sum/sumsq -> deterministic partials ----------------
__global__ __launch_bounds__(256) void k_gather(const float* __restrict__ u, const float* __restrict__ v,
                                                const int* __restrict__ idx, int O,
                                                float* __restrict__ s,
                                                float* __restrict__ gp1, float* __restrict__ gp2){
  __shared__ float r1[256], r2[256];
  int tid = threadIdx.x;
  int Ppar = 256 / O;
  int o = tid % O, g = tid / O;
  int p0 = blockIdx.x*16;
  float cs = 0.f, cs2 = 0.f;
  int IT = 16 / Ppar;
  for (int it = 0; it < IT; ++it){
    int pi = p0 + it*Ppar + g;
    int b = pi / NN;
    const int* il = idx + (size_t)pi*KNNK;
    float vv = v[(size_t)pi*O + o];
    float mx = -FLT_MAX, su = 0.f, su2 = 0.f;
    #pragma unroll
    for (int k = 0; k < KNNK; ++k){
      int m = il[k];
      float um = u[((size_t)b*NN + m)*O + o];
      mx = fmaxf(mx, um); su += um; su2 = fmaf(um, um, su2);
    }
    s[(size_t)pi*O + o] = mx + vv;
    cs += su + (float)KNNK*vv;
    cs2 += su2 + 2.f*vv*su + (float)KNNK*vv*vv;
  }
  r1[tid] = cs; r2[tid] = cs2;
  __syncthreads();
  if (tid < O){
    float t1 = 0.f, t2 = 0.f;
    for (int gg = 0; gg < Ppar; ++gg){ t1 += r1[gg*O + tid]; t2 += r2[gg*O + tid]; }
    gp1[(size_t)tid*GBLK + blockIdx.x] = t1;
    gp2[(size_t)tid*GBLK + blockIdx.x] = t2;
  }
}

// ---------------- deterministic partial reduce: one block per channel ----------------
__global__ __launch_bounds__(256) void k_pred(const float* __restrict__ gp1, const float* __restrict__ gp2,
                                              float* __restrict__ S1, float* __restrict__ S2){
  __shared__ float r1[256], r2[256];
  int o = blockIdx.x, t = threadIdx.x;
  float a = 0.f, b = 0.f;
  #pragma unroll
  for (int i = 0; i < GBLK/256; ++i){
    a += gp1[(size_t)o*GBLK + i*256 + t];
    b += gp2[(size_t)o*GBLK + i*256 + t];
  }
  r1[t] = a; r2[t] = b;
  __syncthreads();
  for (int off = 128; off > 0; off >>= 1){
    if (t < off){ r1[t] += r1[t + off]; r2[t] += r2[t + off]; }
    __syncthreads();
  }
  if (t == 0){ S1[o] = r1[0]; S2[o] = r2[0]; }
}

// ---------------- finalize BN ----------------
__global__ void k_fin(const float* __restrict__ S1, const float* __restrict__ S2,
                      const float* __restrict__ g, const float* __restrict__ bb,
                      int O, float cnt, float* __restrict__ A, float* __restrict__ Bp){
  int o = blockIdx.x*256 + threadIdx.x;
  if (o >= O) return;
  float m = S1[o] / cnt;
  float var = S2[o] / cnt - m*m;
  float sc = g[o] / sqrtf(var + EPSF);
  A[o] = sc; Bp[o] = bb[o] - m*sc;
}

// ---------------- BN + leaky -> h slice ----------------
__global__ void k_bnle(const float* __restrict__ s, const float* __restrict__ A,
                       const float* __restrict__ Bp, int O, int choff, float* __restrict__ h){
  int gid = blockIdx.x*256 + threadIdx.x;
  int row = gid / O, o = gid % O;
  h[(size_t)row*HC + choff + o] = leakyf(fmaf(s[gid], A[o], Bp[o]));
}

// ---------------- column sums of h -> 16 deterministic partials ----------------
__global__ void k_colsum(const float* __restrict__ hh, float* __restrict__ cp){
  __shared__ float red[4][64];
  int c = threadIdx.x & 63, g = threadIdx.x >> 6;
  int cb = blockIdx.x*64;
  int rbase = blockIdx.y*2048;
  float sacc = 0.f;
  for (int r = rbase + g; r < rbase + 2048; r += 4)
    sacc += hh[(size_t)r*HC + cb + c];
  red[g][c] = sacc;
  __syncthreads();
  if (threadIdx.x < 64){
    float t = red[0][c] + red[1][c] + red[2][c] + red[3][c];
    cp[(size_t)blockIdx.y*HC + cb + c] = t;
  }
}

__global__ void k_csred(const float* __restrict__ cp, float* __restrict__ cs){
  int c = blockIdx.x*256 + threadIdx.x;
  if (c >= HC) return;
  float s = 0.f;
  for (int g = 0; g < 16; ++g) s += cp[(size_t)g*HC + c];
  cs[c] = s;
}

// ---------------- SYRK partials ----------------
__global__ __launch_bounds__(256) void k_syrk(const float* __restrict__ hh, float* __restrict__ Gp){
  __shared__ float as[16][132], bs[16][132];
  int tid = threadIdx.x;
  int ib = blockIdx.x*128, jb = blockIdx.y*128;
  int k0 = blockIdx.z*1024;
  int cx = tid & 15, ry = tid >> 4;
  int skk = tid >> 4, scc = (tid & 15)*8;
  float acc[8][8] = {};
  for (int kk0 = k0; kk0 < k0 + 1024; kk0 += 16){
    {
      const float* ra = &hh[(size_t)(kk0 + skk)*HC + ib + scc];
      const float* rb2 = &hh[(size_t)(kk0 + skk)*HC + jb + scc];
      float4 a0 = *(const float4*)ra, a1 = *(const float4*)(ra + 4);
      float4 b0 = *(const float4*)rb2, b1 = *(const float4*)(rb2 + 4);
      *(float4*)&as[skk][scc] = a0; *(float4*)&as[skk][scc+4] = a1;
      *(float4*)&bs[skk][scc] = b0; *(float4*)&bs[skk][scc+4] = b1;
    }
    __syncthreads();
    #pragma unroll
    for (int kk = 0; kk < 16; ++kk){
      float4 a0 = *(const float4*)&as[kk][ry*8];
      float4 a1 = *(const float4*)&as[kk][ry*8+4];
      float4 b0 = *(const float4*)&bs[kk][cx*8];
      float4 b1 = *(const float4*)&bs[kk][cx*8+4];
      float av[8] = {a0.x,a0.y,a0.z,a0.w,a1.x,a1.y,a1.z,a1.w};
      float bv[8] = {b0.x,b0.y,b0.z,b0.w,b1.x,b1.y,b1.z,b1.w};
      #pragma unroll
      for (int i = 0; i < 8; ++i)
        #pragma unroll
        for (int j = 0; j < 8; ++j)
          acc[i][j] = fmaf(av[i], bv[j], acc[i][j]);
    }
    __syncthreads();
  }
  float* gz = Gp + (size_t)blockIdx.z*HC*HC;
  #pragma unroll
  for (int i = 0; i < 8; ++i){
    size_t row = (size_t)(ib + ry*8 + i);
    *(float4*)&gz[row*HC + jb + cx*8]     = make_float4(acc[i][0], acc[i][1], acc[i][2], acc[i][3]);
    *(float4*)&gz[row*HC + jb + cx*8 + 4] = make_float4(acc[i][4], acc[i][5], acc[i][6], acc[i][7]);
  }
}

// ---------------- reduce SYRK partials ----------------
__global__ void k_gred(const float* __restrict__ Gp, float* __restrict__ G){
  int e = blockIdx.x*256 + threadIdx.x;
  float s = 0.f;
  for (int z = 0; z < 32; ++z) s += Gp[(size_t)z*HC*HC + e];
  G[e] = s;
}

// ---------------- quadratic forms ----------------
__global__ __launch_bounds__(256) void k_quad(const float* __restrict__ G, const float* __restrict__ W5,
                                              const float* __restrict__ cs,
                                              float* __restrict__ S1, float* __restrict__ S2){
  __shared__ float wsh[512];
  __shared__ float red[256];
  int o = blockIdx.x, tid = threadIdx.x;
  for (int j = tid; j < 512; j += 256) wsh[j] = W5[(size_t)o*HC + j];
  __syncthreads();
  float q = 0.f;
  for (int i = tid; i < 512; i += 256){
    float wi = wsh[i];
    float rd = 0.f;
    for (int j = 0; j < 512; j += 4){
      float4 gv = *(const float4*)&G[(size_t)i*HC + j];
      rd = fmaf(gv.x, wsh[j], rd); rd = fmaf(gv.y, wsh[j+1], rd);
      rd = fmaf(gv.z, wsh[j+2], rd); rd = fmaf(gv.w, wsh[j+3], rd);
    }
    q = fmaf(wi, rd, q);
  }
  float m = 0.f;
  for (int j = tid; j < 512; j += 256) m = fmaf(wsh[j], cs[j], m);
  red[tid] = q; __syncthreads();
  for (int off = 128; off > 0; off >>= 1){ if (tid < off) red[tid] += red[tid + off]; __syncthreads(); }
  if (tid == 0) S2[o] = red[0];
  __syncthreads();
  red[tid] = m; __syncthreads();
  for (int off = 128; off > 0; off >>= 1){ if (tid < off) red[tid] += red[tid + off]; __syncthreads(); }
  if (tid == 0) S1[o] = red[0];
}

// ---------------- layer5 GEMM: y tile -> BN+leaky -> pooled partials ----------------
__global__ __launch_bounds__(256) void k_gemm5b(const float* __restrict__ hh, const float* __restrict__ W5,
                                                const float* __restrict__ A, const float* __restrict__ Bp,
                                                float* __restrict__ mpart, float* __restrict__ spart){
  __shared__ float hs[16][132];
  __shared__ float ws[16][132];
  int tid = threadIdx.x;
  int rb = blockIdx.x*128, ob = blockIdx.y*128;
  int cx = tid & 15, ry = tid >> 4;
  float acc[8][8] = {};
  for (int c0 = 0; c0 < 512; c0 += 16){
    int rr = tid & 127, q0 = (tid >> 7)*4;
    #pragma unroll
    for (int qq = 0; qq < 2; ++qq){
      int kk = q0 + qq*8;
      float4 hv = *(const float4*)&hh[(size_t)(rb+rr)*HC + c0 + kk];
      hs[kk+0][rr] = hv.x; hs[kk+1][rr] = hv.y; hs[kk+2][rr] = hv.z; hs[kk+3][rr] = hv.w;
      float4 wv = *(const float4*)&W5[(size_t)(ob+rr)*HC + c0 + kk];
      ws[kk+0][rr] = wv.x; ws[kk+1][rr] = wv.y; ws[kk+2][rr] = wv.z; ws[kk+3][rr] = wv.w;
    }
    __syncthreads();
    #pragma unroll
    for (int kk = 0; kk < 16; ++kk){
      float4 a0 = *(const float4*)&hs[kk][ry*8];
      float4 a1 = *(const float4*)&hs[kk][ry*8+4];
      float4 b0 = *(const float4*)&ws[kk][cx*8];
      float4 b1 = *(const float4*)&ws[kk][cx*8+4];
      float av[8] = {a0.x,a0.y,a0.z,a0.w,a1.x,a1.y,a1.z,a1.w};
      float bv[8] = {b0.x,b0.y,b0.z,b0.w,b1.x,b1.y,b1.z,b1.w};
      #pragma unroll
      for (int i = 0; i < 8; ++i)
        #pragma unroll
        for (int j = 0; j < 8; ++j)
          acc[i][j] = fmaf(av[i], bv[j], acc[i][j]);
    }
    __syncthreads();
  }
  float Ao[8], Bo[8];
  #pragma unroll
  for (int j = 0; j < 8; ++j){ Ao[j] = A[ob + cx*8 + j]; Bo[j] = Bp[ob + cx*8 + j]; }
  float cmx[8], csm[8];
  #pragma unroll
  for (int j = 0; j < 8; ++j){ cmx[j] = -FLT_MAX; csm[j] = 0.f; }
  #pragma unroll
  for (int i = 0; i < 8; ++i)
    #pragma unroll
    for (int j = 0; j < 8; ++j){
      float a = leakyf(fmaf(acc[i][j], Ao[j], Bo[j]));
      cmx[j] = fmaxf(cmx[j], a); csm[j] += a;
    }
  __syncthreads();
  #pragma unroll
  for (int j = 0; j < 8; ++j){ hs[ry][cx*8 + j] = cmx[j]; ws[ry][cx*8 + j] = csm[j]; }
  __syncthreads();
  if (tid < 128){
    float mx = -FLT_MAX, sm = 0.f;
    for (int g = 0; g < 16; ++g){ mx = fmaxf(mx, hs[g][tid]); sm += ws[g][tid]; }
    int bbi = rb / NN, ntile = (rb % NN) >> 7;
    int o = ob + tid;
    mpart[((size_t)bbi*O5 + o)*16 + ntile] = mx;
    spart[((size_t)bbi*O5 + o)*16 + ntile] = sm;
  }
}

// ---------------- pool partials -> p ----------------
__global__ void k_pool(const float* __restrict__ mpart, const float* __restrict__ spart,
                       float* __restrict__ p){
  int gid = blockIdx.x*256 + threadIdx.x;
  if (gid >= BB*O5) return;
  int b = gid / O5, o = gid % O5;
  const float* mp = mpart + (size_t)(b*O5 + o)*16;
  const float* sp = spart + (size_t)(b*O5 + o)*16;
  float mx = -FLT_MAX, sm = 0.f;
  for (int t = 0; t < 16; ++t){ mx = fmaxf(mx, mp[t]); sm += sp[t]; }
  p[(size_t)b*2048 + o] = mx;
  p[(size_t)b*2048 + 1024 + o] = sm * (1.f/2048.f);
}

// ---------------- z = p @ Wl.T then BN over batch ----------------
__global__ __launch_bounds__(256) void k_final(const float* __restrict__ p, const float* __restrict__ Wl,
                                               const float* __restrict__ g6, const float* __restrict__ b6,
                                               float* __restrict__ out){
  __shared__ float red[16][257];
  int oc = blockIdx.x, tid = threadIdx.x;
  float acc[16] = {};
  for (int j = tid; j < 2048; j += 256){
    float w = Wl[(size_t)oc*2048 + j];
    #pragma unroll
    for (int b = 0; b < 16; ++b) acc[b] = fmaf(p[(size_t)b*2048 + j], w, acc[b]);
  }
  #pragma unroll
  for (int b = 0; b < 16; ++b) red[b][tid] = acc[b];
  __syncthreads();
  for (int off = 128; off > 0; off >>= 1){
    if (tid < off){
      #pragma unroll
      for (int b = 0; b < 16; ++b) red[b][tid] += red[b][tid + off];
    }
    __syncthreads();
  }
  if (tid == 0){
    float m = 0.f;
    for (int b = 0; b < 16; ++b) m += red[b][0];
    m *= (1.f/16.f);
    float var = 0.f;
    for (int b = 0; b < 16; ++b){ float d = red[b][0] - m; var = fmaf(d, d, var); }
    var *= (1.f/16.f);
    float sc = g6[oc] / sqrtf(var + EPSF);
    for (int b = 0; b < 16; ++b) out[(size_t)b*256 + oc] = (red[b][0] - m)*sc + b6[oc];
  }
}

extern "C" void kernel_launch(void* const* d_in, const int* in_sizes, int n_in,
                              void* d_out, int out_size, void* d_ws, size_t ws_size,
                              hipStream_t stream){
  const float* x  = (const float*)d_in[0];
  const float* W1 = (const float*)d_in[1];  const float* g1 = (const float*)d_in[2];  const float* b1 = (const float*)d_in[3];
  const float* W2 = (const float*)d_in[4];  const float* g2 = (const float*)d_in[5];  const float* b2 = (const float*)d_in[6];
  const float* W3 = (const float*)d_in[7];  const float* g3 = (const float*)d_in[8];  const float* b3 = (const float*)d_in[9];
  const float* W4 = (const float*)d_in[10]; const float* g4 = (const float*)d_in[11]; const float* b4 = (const float*)d_in[12];
  const float* W5 = (const float*)d_in[13]; const float* g5 = (const float*)d_in[14]; const float* b5 = (const float*)d_in[15];
  const float* Wl = (const float*)d_in[16]; const float* g6 = (const float*)d_in[17]; const float* b6 = (const float*)d_in[18];
  float* out = (float*)d_out;

  float* ws = (float*)d_ws;
  size_t off = 0;
  auto alloc = [&](size_t n){ float* pp = ws + off; off += n; return pp; };
  float* h    = alloc((size_t)BB*NN*HC);     // 64 MB
  float* u    = alloc((size_t)BB*NN*256);    // 32 MB (aliased by Gp after layer 4)
  float* v    = alloc((size_t)BB*NN*256);
  float* s    = alloc((size_t)BB*NN*256);
  float* xP   = alloc((size_t)BB*NN*4);
  float* sqn  = alloc((size_t)BB*NN);
  int*   idx  = (int*)alloc((size_t)BB*NN*KNNK);
  float* wu   = alloc(256*128);
  float* wv   = alloc(256*128);
  float* S1   = alloc(1024);
  float* S2   = alloc(1024);
  float* Ab   = alloc(1024);
  float* Bb   = alloc(1024);
  float* mpart= alloc((size_t)BB*O5*16);
  float* spart= alloc((size_t)BB*O5*16);
  float* pbuf = alloc((size_t)BB*2048);
  float* G    = alloc((size_t)HC*HC);
  float* cs   = alloc(HC);
  float* cp   = alloc((size_t)16*HC);
  float* gp1  = alloc((size_t)256*GBLK);     // 2 MB deterministic gather partials
  float* gp2  = alloc((size_t)256*GBLK);
  float* Gp   = u;   // 32 z-chunks x 512x512 = 32 MB, reuses u (dead after layer 4)

  k_transpose<<<(BB*NN)/256, 256, 0, stream>>>(x, xP);

  struct Cfg { const float* xin; int xs, C, O, choff; const float* W; const float* g; const float* bb; };
  Cfg cfg[4] = {
    { xP,    4,   3,   64,   0, W1, g1, b1 },
    { h,     HC,  64,  64,  64, W2, g2, b2 },
    { h+64,  HC,  64, 128, 128, W3, g3, b3 },
    { h+128, HC, 128, 256, 256, W4, g4, b4 },
  };

  for (int i = 0; i < 4; ++i){
    const Cfg& c = cfg[i];
    k_sqn<<<(BB*NN)/256, 256, 0, stream>>>(c.xin, c.xs, c.C, sqn);
    if (c.C == 3)       k_knn<3><<<(BB*NN)/16, 256, 0, stream>>>(c.xin, c.xs, sqn, idx);
    else if (c.C == 64) k_knn<64><<<(BB*NN)/16, 256, 0, stream>>>(c.xin, c.xs, sqn, idx);
    else                k_knn<128><<<(BB*NN)/16, 256, 0, stream>>>(c.xin, c.xs, sqn, idx);
    int OC = c.O * c.C;
    k_wprep<<<(OC + 255)/256, 256, 0, stream>>>(c.W, c.O, c.C, wu, wv);
    k_uv<<<dim3((BB*NN)/64, c.O/64), 256, 0, stream>>>(c.xin, c.xs, c.C, wu, wv, c.O, u, v);
    k_gather<<<GBLK, 256, 0, stream>>>(u, v, idx, c.O, s, gp1, gp2);
    k_pred<<<c.O, 256, 0, stream>>>(gp1, gp2, S1, S2);
    k_fin<<<4, 256, 0, stream>>>(S1, S2, c.g, c.bb, c.O, (float)((size_t)BB*NN*KNNK), Ab, Bb);
    k_bnle<<<((size_t)BB*NN*c.O)/256, 256, 0, stream>>>(s, Ab, Bb, c.O, c.choff, h);
  }

  // layer 5 stats via covariance: S2 = w^T (h^T h) w, S1 = w . colsum(h)
  k_colsum<<<dim3(8, 16), 256, 0, stream>>>(h, cp);
  k_csred<<<2, 256, 0, stream>>>(cp, cs);
  k_syrk<<<dim3(4, 4, 32), 256, 0, stream>>>(h, Gp);
  k_gred<<<(HC*HC)/256, 256, 0, stream>>>(Gp, G);
  k_quad<<<O5, 256, 0, stream>>>(G, W5, cs, S1, S2);
  k_fin<<<4, 256, 0, stream>>>(S1, S2, g5, b5, O5, (float)((size_t)BB*NN), Ab, Bb);
  k_gemm5b<<<dim3((BB*NN)/128, O5/128), 256, 0, stream>>>(h, W5, Ab, Bb, mpart, spart);
  k_pool<<<(BB*O5)/256, 256, 0, stream>>>(mpart, spart, pbuf);

  k_final<<<256, 256, 0, stream>>>(pbuf, Wl, g6, b6, out);
}